// Round 8
// baseline (187.337 us; speedup 1.0000x reference)
//
#include <hip/hip_runtime.h>

// RaggedAttention on MI355X — bf16 MFMA pipeline.
// XP bf16[32768][256]; WCAT bf16[768][256] ([f][c] = B^T input);
// QKVp bf16[32768][768]  (f<256: Q pre-scaled by log2e/sqrt(32); [256,512): K; [512,768): V)
// Vt bf16[bh][32][512] (vtrans; overlays XP — XP dead by then); Y bf16[32768][256].
// MFMA 16x16x32_bf16 mappings (HW-verified):
//   A-frag: lane holds A[m=lane&15][k=(lane>>4)*8+j]
//   B-frag: lane holds B[k=(lane>>4)*8+j][n=lane&15]  (row-major [n][k] source)
//   C/D   : lane reg r holds D[row=(lane>>4)*4+r][col=lane&15]
// r7 lesson: attn FETCH is near-minimal (41.5MB) but VALU 45%/occupancy 21% ->
// execution/latency bound, capped at 4 blocks/CU. This round: attn 2048x128
// blocks (8 blocks/CU), out_gemm m-split to 768 blocks (3/CU).

typedef __attribute__((ext_vector_type(8))) short short8;
typedef __attribute__((ext_vector_type(4))) float f32x4;

#define N_TOTAL 24576
#define B_ 64
#define T_ 512
#define DM 256
#define NH 8
#define HD 32
#define F3 768

#define QSCALE 0.25503463f   // log2(e)/sqrt(HD), folded into Q
#define VSP 520              // vtrans LDS row stride (shorts)

__device__ __forceinline__ unsigned short f2bf(float f) {
  unsigned int u = __float_as_uint(f);
  u += 0x7fffu + ((u >> 16) & 1u);   // RNE
  return (unsigned short)(u >> 16);
}

__device__ __forceinline__ void gl_lds16(const void* g, void* l) {
  __builtin_amdgcn_global_load_lds(
      (const __attribute__((address_space(1))) unsigned int*)g,
      (__attribute__((address_space(3))) unsigned int*)l, 16, 0, 0);
}

// ---------------- kernel 0: gather + bf16 cast + weight packing ----------------
__global__ __launch_bounds__(256) void pack_kernel(
    const float* __restrict__ x, const float* __restrict__ Wq,
    const float* __restrict__ Wk, const float* __restrict__ Wv,
    const float* __restrict__ Wp, const float* __restrict__ bq,
    const float* __restrict__ bk, const float* __restrict__ bv,
    const int* __restrict__ idx,
    short* __restrict__ XP, short* __restrict__ WCAT, short* __restrict__ WPb,
    float* __restrict__ BCAT) {
  int gid = blockIdx.x * 256 + threadIdx.x;
  if (gid < 768)
    BCAT[gid] = (gid < 256) ? bq[gid] : (gid < 512 ? bk[gid - 256] : bv[gid - 512]);
  const float* src;
  short* dst;
  if (gid < 1048576) {
    int row = gid >> 5, seg = gid & 31;
    src = x + (size_t)idx[row] * DM + seg * 8;
    dst = XP + (size_t)gid * 8;
  } else if (gid < 1073152) {
    int u = gid - 1048576;
    int f = u >> 5, seg = u & 31;
    const float* W = (f < 256) ? Wq : ((f < 512) ? Wk : Wv);
    src = W + (size_t)(f & 255) * DM + seg * 8;
    dst = WCAT + (size_t)u * 8;
  } else {
    int u = gid - 1073152;
    src = Wp + (size_t)u * 8;
    dst = WPb + (size_t)u * 8;
  }
  const float4* s4 = (const float4*)src;
  float4 a = s4[0], b = s4[1];
  short8 o;
  o[0] = (short)f2bf(a.x); o[1] = (short)f2bf(a.y);
  o[2] = (short)f2bf(a.z); o[3] = (short)f2bf(a.w);
  o[4] = (short)f2bf(b.x); o[5] = (short)f2bf(b.y);
  o[6] = (short)f2bf(b.z); o[7] = (short)f2bf(b.w);
  *(short8*)dst = o;
}

// ---------------- kernel 1: QKV GEMM (M=32768,N=768,K=256) --------------------
// 128x128 tile, 4 waves (64x64). A+B staged via DMA, 3 slabs, vmcnt(4) pipeline.
__global__ __launch_bounds__(256) void qkv_gemm(
    const short* __restrict__ XP, const short* __restrict__ WCAT,
    const float* __restrict__ BCAT, unsigned short* __restrict__ QKVp) {
  __shared__ __align__(16) char smem[3 * 16384];
  int tid = threadIdx.x;
  int lane = tid & 63, w = tid >> 6;
  int i = lane & 15, q = lane >> 4;
  int m0 = blockIdx.x * 128, n0 = blockIdx.y * 128;
  int wm = (w & 1) * 64, wn = (w >> 1) * 64;
  int csa = q ^ ((i >> 1) & 3);

  f32x4 zf = {0.f, 0.f, 0.f, 0.f};
  f32x4 acc[4][4];
#pragma unroll
  for (int mt = 0; mt < 4; mt++)
#pragma unroll
    for (int nt = 0; nt < 4; nt++) acc[mt][nt] = zf;

  auto stage = [&](int k, int s) {
#pragma unroll
    for (int p = 0; p < 2; p++) {
      int U = p * 256 + tid;
      int row = U >> 2, c = U & 3;
      int cs = c ^ ((row >> 1) & 3);
      gl_lds16(XP + (size_t)(m0 + row) * DM + k * 32 + cs * 8,
               smem + s * 16384 + U * 16);
      gl_lds16(WCAT + (size_t)(n0 + row) * DM + k * 32 + cs * 8,
               smem + s * 16384 + 8192 + U * 16);
    }
  };

  stage(0, 0);
  stage(1, 1);
#pragma unroll
  for (int k = 0; k < 8; k++) {
    if (k == 7)
      asm volatile("s_waitcnt vmcnt(0) lgkmcnt(0)\ns_barrier" ::: "memory");
    else
      asm volatile("s_waitcnt vmcnt(4) lgkmcnt(0)\ns_barrier" ::: "memory");
    const short* Asb = (const short*)(smem + (k % 3) * 16384);
    const short* Bsb = Asb + 4096;
    short8 a[4], bfr[4];
#pragma unroll
    for (int mt = 0; mt < 4; mt++)
      a[mt] = *(const short8*)&Asb[(wm + mt * 16 + i) * 32 + csa * 8];
#pragma unroll
    for (int nt = 0; nt < 4; nt++)
      bfr[nt] = *(const short8*)&Bsb[(wn + nt * 16 + i) * 32 + csa * 8];
    if (k < 6) stage(k + 2, (k + 2) % 3);
#pragma unroll
    for (int mt = 0; mt < 4; mt++)
#pragma unroll
      for (int nt = 0; nt < 4; nt++)
        acc[mt][nt] = __builtin_amdgcn_mfma_f32_16x16x32_bf16(a[mt], bfr[nt], acc[mt][nt], 0, 0, 0);
  }

  float scale = (n0 < 256) ? QSCALE : 1.0f;
#pragma unroll
  for (int nt = 0; nt < 4; nt++) {
    int f = n0 + wn + nt * 16 + i;
    float bias = BCAT[f];
#pragma unroll
    for (int mt = 0; mt < 4; mt++) {
#pragma unroll
      for (int r = 0; r < 4; r++) {
        int token = m0 + wm + mt * 16 + q * 4 + r;
        QKVp[(size_t)token * F3 + f] = f2bf((acc[mt][nt][r] + bias) * scale);
      }
    }
  }
}

// ---------------- kernel 1b: V transpose (QKVp V-part -> Vt[bh][32][512]) -----
__global__ __launch_bounds__(256) void vtrans_kernel(
    const unsigned short* __restrict__ QKVp, unsigned short* __restrict__ Vt) {
  __shared__ short Vl[HD * VSP];
  int bh = blockIdx.x;
  int b = bh >> 3, h = bh & 7;
  int tid = threadIdx.x;
  const unsigned short* src = QKVp + (size_t)b * T_ * F3 + 512 + h * HD;
  int seg = tid & 3, trow = tid >> 2;
#pragma unroll
  for (int l = 0; l < 8; l++) {
    int t = trow + l * 64;
    short8 v = *(const short8*)&src[(size_t)t * F3 + seg * 8];
#pragma unroll
    for (int j = 0; j < 8; j++) Vl[(seg * 8 + j) * VSP + t] = v[j];
  }
  __syncthreads();
  int d = tid >> 3, tc = tid & 7;   // 32 d x 8 t-chunks
#pragma unroll
  for (int l = 0; l < 8; l++) {
    int t = (tc + l * 8) * 8;
    short8 v = *(const short8*)&Vl[d * VSP + t];
    *(short8*)&Vt[((size_t)bh * HD + d) * T_ + t] = v;
  }
}

// ---------------- kernel 2: attention ----------------
// 2048 blocks x 128 threads (2 waves); wave = 64 t-rows of one (b,h); s-step 32.
// Swizzle: all 4 quarter-blocks of a bh share bx%8 (same XCD, adjacent dispatch).
// K rows interleaved (lane i <-> s=2i,2i+1). V from global Vt (coalesced).
// Mask pre-exp; denominator via ones-column MFMA on the same truncated P.
__global__ __launch_bounds__(128) void attn_kernel(
    const unsigned short* __restrict__ QKVp, const unsigned short* __restrict__ Vt,
    const int* __restrict__ batch, unsigned short* __restrict__ Y) {
  __shared__ __align__(16) short pscr[2][64 * 40];  // 10,240 B
  __shared__ int sbat[T_];                          //  2,048 B
  int tid = threadIdx.x, w = tid >> 6, lane = tid & 63;
  int i = lane & 15, q = lane >> 4;
  int bx = blockIdx.x;
  int bh = ((bx >> 5) << 3) | (bx & 7);
  int quarter = (bx >> 3) & 3;
  int b = bh >> 3, h = bh & 7;
  int t0 = quarter * 128 + w * 64;
  const unsigned short* Tok = QKVp + (size_t)b * T_ * F3;
  const unsigned short* Vb = Vt + (size_t)bh * HD * T_;

  *(int4*)&sbat[tid * 4] = *(const int4*)&batch[b * T_ + tid * 4];
  __syncthreads();

  short* pw = &pscr[w][0];

  short8 qf[4];
  int btv[4][4];
#pragma unroll
  for (int mt = 0; mt < 4; mt++)
    qf[mt] = *(const short8*)&Tok[(size_t)(t0 + mt * 16 + i) * F3 + h * HD + q * 8];
#pragma unroll
  for (int mt = 0; mt < 4; mt++) {
    int4 t4 = *(int4*)&sbat[t0 + mt * 16 + q * 4];
    btv[mt][0] = t4.x; btv[mt][1] = t4.y; btv[mt][2] = t4.z; btv[mt][3] = t4.w;
  }

  // ones B-fragment: B[k][n] = (n==0) ? 1.0bf16 : 0
  unsigned short ob = (i == 0) ? (unsigned short)0x3F80 : (unsigned short)0;
  short8 ones = {(short)ob, (short)ob, (short)ob, (short)ob,
                 (short)ob, (short)ob, (short)ob, (short)ob};

  f32x4 zf = {0.f, 0.f, 0.f, 0.f};
  f32x4 o[4][2], lacc[4];
#pragma unroll
  for (int mt = 0; mt < 4; mt++) {
    o[mt][0] = zf; o[mt][1] = zf; lacc[mt] = zf;
  }

  const unsigned short* Kcol = Tok + 256 + h * HD + q * 8;
  short8 k0f = *(const short8*)&Kcol[(size_t)(2 * i) * F3];
  short8 k1f = *(const short8*)&Kcol[(size_t)(2 * i + 1) * F3];
  int bs0 = sbat[2 * i], bs1 = sbat[2 * i + 1];

  for (int s0 = 0; s0 < T_; s0 += 32) {
    short8 ck0 = k0f, ck1 = k1f;
    int cb0 = bs0, cb1 = bs1;
    if (s0 + 32 < T_) {
      k0f = *(const short8*)&Kcol[(size_t)(s0 + 32 + 2 * i) * F3];
      k1f = *(const short8*)&Kcol[(size_t)(s0 + 32 + 2 * i + 1) * F3];
      bs0 = sbat[s0 + 32 + 2 * i];
      bs1 = sbat[s0 + 32 + 2 * i + 1];
    }
    short8 v0f = *(const short8*)&Vb[(size_t)i * T_ + s0 + q * 8];
    short8 v1f = *(const short8*)&Vb[(size_t)(16 + i) * T_ + s0 + q * 8];
#pragma unroll
    for (int mt = 0; mt < 4; mt++) {
      f32x4 st0 = __builtin_amdgcn_mfma_f32_16x16x32_bf16(qf[mt], ck0, zf, 0, 0, 0);
      f32x4 st1 = __builtin_amdgcn_mfma_f32_16x16x32_bf16(qf[mt], ck1, zf, 0, 0, 0);
#pragma unroll
      for (int r = 0; r < 4; r++) {
        float m0v = (btv[mt][r] == cb0) ? -1e9f : st0[r];
        float m1v = (btv[mt][r] == cb1) ? -1e9f : st1[r];
        unsigned e0 = __float_as_uint(__builtin_amdgcn_exp2f(m0v));
        unsigned e1 = __float_as_uint(__builtin_amdgcn_exp2f(m1v));
        unsigned pk = __builtin_amdgcn_perm(e1, e0, 0x07060302u);
        *(unsigned*)&pw[(mt * 16 + q * 4 + r) * 40 + 2 * i] = pk;
      }
    }
#pragma unroll
    for (int mt = 0; mt < 4; mt++) {
      short8 pa = *(short8*)&pw[(mt * 16 + i) * 40 + q * 8];
      o[mt][0] = __builtin_amdgcn_mfma_f32_16x16x32_bf16(pa, v0f, o[mt][0], 0, 0, 0);
      o[mt][1] = __builtin_amdgcn_mfma_f32_16x16x32_bf16(pa, v1f, o[mt][1], 0, 0, 0);
      lacc[mt] = __builtin_amdgcn_mfma_f32_16x16x32_bf16(pa, ones, lacc[mt], 0, 0, 0);
    }
  }

#pragma unroll
  for (int mt = 0; mt < 4; mt++) {
#pragma unroll
    for (int r = 0; r < 4; r++) {
      float lv = __shfl(lacc[mt][r], lane & 48, 64);  // col 0 of this row-quad
      float inv = __builtin_amdgcn_rcpf(lv);
      size_t yb = ((size_t)b * T_ + t0 + mt * 16 + q * 4 + r) * DM + h * HD;
      Y[yb + i] = f2bf(o[mt][0][r] * inv);
      Y[yb + 16 + i] = f2bf(o[mt][1][r] * inv);
    }
  }
}

// ---------------- kernel 3: output GEMM, gathered A rows ----------------------
// out[i][f] = sum_c Y[inv[i]][c] * Wp[f][c] + bp[f]; M=24576,N=256,K=256.
// m-split: 768 blocks of 64m x 128n (3 blocks/CU), wave = 32m x 64n.
// Stage = 3 DMA insts (A 1 + B 2); vmcnt(3) keeps stage k+1 in flight.
__global__ __launch_bounds__(256) void out_gemm(
    const short* __restrict__ Y, const short* __restrict__ WPb,
    const float* __restrict__ bp, const int* __restrict__ inv,
    float* __restrict__ out) {
  __shared__ __align__(16) char smem[3 * 12288];
  int tid = threadIdx.x;
  int lane = tid & 63, w = tid >> 6;
  int i = lane & 15, q = lane >> 4;
  int m0 = blockIdx.x * 64, n0 = blockIdx.y * 128;
  int wm = (w & 1) * 32, wn = (w >> 1) * 64;
  int csa = q ^ ((i >> 1) & 3);

  int iv0 = inv[m0 + (tid >> 2)];

  f32x4 zf = {0.f, 0.f, 0.f, 0.f};
  f32x4 acc[2][4];
#pragma unroll
  for (int mt = 0; mt < 2; mt++)
#pragma unroll
    for (int nt = 0; nt < 4; nt++) acc[mt][nt] = zf;

  auto stage = [&](int k, int s) {
    char* sb = smem + s * 12288;
    {
      int row = tid >> 2, c = tid & 3;
      int cs = c ^ ((row >> 1) & 3);
      gl_lds16(Y + (size_t)iv0 * DM + k * 32 + cs * 8, sb + tid * 16);
    }
#pragma unroll
    for (int p = 0; p < 2; p++) {
      int U = p * 256 + tid;
      int row = U >> 2, c = U & 3;
      int cs = c ^ ((row >> 1) & 3);
      gl_lds16(WPb + (size_t)(n0 + row) * DM + k * 32 + cs * 8,
               sb + 4096 + U * 16);
    }
  };

  stage(0, 0);
  stage(1, 1);
#pragma unroll
  for (int k = 0; k < 8; k++) {
    if (k == 7)
      asm volatile("s_waitcnt vmcnt(0) lgkmcnt(0)\ns_barrier" ::: "memory");
    else
      asm volatile("s_waitcnt vmcnt(3) lgkmcnt(0)\ns_barrier" ::: "memory");
    const short* Asb = (const short*)(smem + (k % 3) * 12288);
    const short* Bsb = Asb + 2048;
    short8 a[2], bfr[4];
#pragma unroll
    for (int mt = 0; mt < 2; mt++)
      a[mt] = *(const short8*)&Asb[(wm + mt * 16 + i) * 32 + csa * 8];
#pragma unroll
    for (int nt = 0; nt < 4; nt++)
      bfr[nt] = *(const short8*)&Bsb[(wn + nt * 16 + i) * 32 + csa * 8];
    if (k < 6) stage(k + 2, (k + 2) % 3);
#pragma unroll
    for (int mt = 0; mt < 2; mt++)
#pragma unroll
      for (int nt = 0; nt < 4; nt++)
        acc[mt][nt] = __builtin_amdgcn_mfma_f32_16x16x32_bf16(a[mt], bfr[nt], acc[mt][nt], 0, 0, 0);
  }

#pragma unroll
  for (int nt = 0; nt < 4; nt++) {
    int f = n0 + wn + nt * 16 + i;
    float bias = bp[f];
#pragma unroll
    for (int mt = 0; mt < 2; mt++) {
#pragma unroll
      for (int r = 0; r < 4; r++) {
        int row = m0 + wm + mt * 16 + q * 4 + r;
        out[(size_t)row * DM + f] = acc[mt][nt][r] + bias;
      }
    }
  }
}

// ---------------- launch ----------------
extern "C" void kernel_launch(void* const* d_in, const int* in_sizes, int n_in,
                              void* d_out, int out_size, void* d_ws, size_t ws_size,
                              hipStream_t stream) {
  const float* x = (const float*)d_in[0];
  const float* Wq = (const float*)d_in[1];
  const float* bq = (const float*)d_in[2];
  const float* Wk = (const float*)d_in[3];
  const float* bk = (const float*)d_in[4];
  const float* Wv = (const float*)d_in[5];
  const float* bv = (const float*)d_in[6];
  const float* Wp = (const float*)d_in[7];
  const float* bp = (const float*)d_in[8];
  const int* idx = (const int*)d_in[9];
  const int* batch = (const int*)d_in[10];
  const int* inv = (const int*)d_in[11];
  float* out = (float*)d_out;

  char* ws = (char*)d_ws;
  short* XP = (short*)(ws + 0);                            // 16,777,216 B
  short* WCAT = (short*)(ws + 16777216);                   //    393,216 B
  short* WPb = (short*)(ws + 17170432);                    //    131,072 B
  float* BCAT = (float*)(ws + 17301504);                   //      3,072 B
  unsigned short* QKVp = (unsigned short*)(ws + 17304576); // 50,331,648 B
  unsigned short* Yb = (unsigned short*)(ws + 67636224);   // 16,777,216 B
  // Vt reuses XP's region (XP dead after qkv_gemm)
  unsigned short* Vt = (unsigned short*)(ws + 0);

  pack_kernel<<<4224, 256, 0, stream>>>(x, Wq, Wk, Wv, Wp, bq, bk, bv, idx,
                                        XP, WCAT, WPb, BCAT);
  qkv_gemm<<<dim3(256, 6), 256, 0, stream>>>(XP, WCAT, BCAT, QKVp);
  vtrans_kernel<<<512, 256, 0, stream>>>(QKVp, Vt);
  attn_kernel<<<2048, 128, 0, stream>>>(QKVp, Vt, batch, Yb);
  out_gemm<<<dim3(384, 2), 256, 0, stream>>>((const short*)Yb, WPb, bp, inv, out);
}

// Round 9
// 181.610 us; speedup vs baseline: 1.0315x; 1.0315x over previous
//
#include <hip/hip_runtime.h>

// RaggedAttention on MI355X — bf16 MFMA pipeline, fused traffic.
// WCAT bf16[768][256] ([f][c] = B^T input, rows 0..511 = Q|K, 512..767 = V);
// QKp bf16[32768][512]  (Q pre-scaled by log2e/sqrt(32) | K), stride 512;
// Vt bf16[bh][32][512] (written by qkv V-blocks via LDS transpose);
// Y bf16[32768][256].
// MFMA 16x16x32_bf16 mappings (HW-verified):
//   A-frag: lane holds A[m=lane&15][k=(lane>>4)*8+j]
//   B-frag: lane holds B[k=(lane>>4)*8+j][n=lane&15]  (row-major [n][k] source)
//   C/D   : lane reg r holds D[row=(lane>>4)*4+r][col=lane&15]
// r8 lesson: attn occupancy pinned ~20% regardless of grid shape -> per-wave
// critical path (exp chain + LDS write->read bubble) is the limiter. This
// round: P double-buffer software pipeline (write P(it+1) while PV-consuming
// P(it)) + K/V register prefetch. qkv fuses x-gather (fp32 DMA + in-kernel
// bf16 pack) and V-transpose (epilogue LDS transpose -> Vt), removing the
// pack-XP roundtrip and the vtrans kernel (~67MB less traffic).

typedef __attribute__((ext_vector_type(8))) short short8;
typedef __attribute__((ext_vector_type(4))) float f32x4;

#define N_TOTAL 24576
#define B_ 64
#define T_ 512
#define DM 256
#define NH 8
#define HD 32
#define F2 512

#define QSCALE 0.25503463f   // log2(e)/sqrt(HD), folded into Q
#define PSTR 40              // pscr row stride (shorts): 80B, 16B-aligned rows

__device__ __forceinline__ unsigned short f2bf(float f) {
  unsigned int u = __float_as_uint(f);
  u += 0x7fffu + ((u >> 16) & 1u);   // RNE
  return (unsigned short)(u >> 16);
}

__device__ __forceinline__ void gl_lds16(const void* g, void* l) {
  __builtin_amdgcn_global_load_lds(
      (const __attribute__((address_space(1))) unsigned int*)g,
      (__attribute__((address_space(3))) unsigned int*)l, 16, 0, 0);
}

// ---------------- kernel 0: weight packing only (x-gather fused into qkv) -----
__global__ __launch_bounds__(256) void pack_kernel(
    const float* __restrict__ Wq, const float* __restrict__ Wk,
    const float* __restrict__ Wv, const float* __restrict__ Wp,
    const float* __restrict__ bq, const float* __restrict__ bk,
    const float* __restrict__ bv,
    short* __restrict__ WCAT, short* __restrict__ WPb, float* __restrict__ BCAT) {
  int gid = blockIdx.x * 256 + threadIdx.x;
  if (gid < 768)
    BCAT[gid] = (gid < 256) ? bq[gid] : (gid < 512 ? bk[gid - 256] : bv[gid - 512]);
  const float* src;
  short* dst;
  if (gid < 24576) {
    int f = gid >> 5, seg = gid & 31;
    const float* W = (f < 256) ? Wq : ((f < 512) ? Wk : Wv);
    src = W + (size_t)(f & 255) * DM + seg * 8;
    dst = WCAT + (size_t)gid * 8;
  } else {
    int u = gid - 24576;
    src = Wp + (size_t)u * 8;
    dst = WPb + (size_t)u * 8;
  }
  const float4* s4 = (const float4*)src;
  float4 a = s4[0], b = s4[1];
  short8 o;
  o[0] = (short)f2bf(a.x); o[1] = (short)f2bf(a.y);
  o[2] = (short)f2bf(a.z); o[3] = (short)f2bf(a.w);
  o[4] = (short)f2bf(b.x); o[5] = (short)f2bf(b.y);
  o[6] = (short)f2bf(b.z); o[7] = (short)f2bf(b.w);
  *(short8*)dst = o;
}

// ---------------- kernel 1: QKV GEMM, x gathered in fp32, fused V-transpose ---
// 128x128 tile, 4 waves (64x64). A staged fp32 (16KB/slab, 4 DMA), B bf16
// (8KB/slab, 2 DMA); 3 slabs; vmcnt(6) pipeline. A frag: 2x ds_read_b128 fp32
// + half-up pack (v_add+v_perm). y<4 -> QKp store; y>=4 -> Vt via LDS transpose.
__global__ __launch_bounds__(256) void qkv_gemm(
    const float* __restrict__ x, const int* __restrict__ idx,
    const short* __restrict__ WCAT, const float* __restrict__ BCAT,
    unsigned short* __restrict__ QKp, unsigned short* __restrict__ Vt) {
  __shared__ __align__(16) char smem[3 * 16384 + 3 * 8192];  // A slabs | B slabs
  int tid = threadIdx.x;
  int lane = tid & 63, w = tid >> 6;
  int i = lane & 15, q = lane >> 4;
  int m0 = blockIdx.x * 128, n0 = blockIdx.y * 128;
  int wm = (w & 1) * 64, wn = (w >> 1) * 64;
  int csb = q ^ ((i >> 1) & 3);     // B read swizzle
  char* smB = smem + 3 * 16384;

  // gather rows: thread p-th DMA covers row p*32 + (tid>>3)
  int ivp[4];
#pragma unroll
  for (int p = 0; p < 4; p++) ivp[p] = idx[m0 + p * 32 + (tid >> 3)];

  auto stage = [&](int k, int s) {
    // A: 1024 slots of 16B; slot U=(p*256+tid): row=U>>3, cslot=U&7, data chunk = cslot^(row&7)
#pragma unroll
    for (int p = 0; p < 4; p++) {
      int U = p * 256 + tid;
      int cg = (U & 7) ^ ((tid >> 3) & 7);  // row&7 == (tid>>3)&7
      gl_lds16(x + (size_t)ivp[p] * DM + k * 32 + cg * 4, smem + s * 16384 + U * 16);
    }
    // B: 512 slots; slot V=(p*256+tid): row=V>>2, c=V&3, swizzle c^((row>>1)&3)
#pragma unroll
    for (int p = 0; p < 2; p++) {
      int U = p * 256 + tid;
      int row = U >> 2, c = U & 3;
      int cs = c ^ ((row >> 1) & 3);
      gl_lds16(WCAT + (size_t)(n0 + row) * DM + k * 32 + cs * 8,
               smB + s * 8192 + U * 16);
    }
  };

  f32x4 zf = {0.f, 0.f, 0.f, 0.f};
  f32x4 acc[4][4];
#pragma unroll
  for (int mt = 0; mt < 4; mt++)
#pragma unroll
    for (int nt = 0; nt < 4; nt++) acc[mt][nt] = zf;

  stage(0, 0);
  stage(1, 1);
#pragma unroll
  for (int k = 0; k < 8; k++) {
    if (k == 7)
      asm volatile("s_waitcnt vmcnt(0) lgkmcnt(0)\ns_barrier" ::: "memory");
    else
      asm volatile("s_waitcnt vmcnt(6) lgkmcnt(0)\ns_barrier" ::: "memory");
    const float* Asb = (const float*)(smem + (k % 3) * 16384);
    const short* Bsb = (const short*)(smB + (k % 3) * 8192);
    short8 a[4], bfr[4];
#pragma unroll
    for (int mt = 0; mt < 4; mt++) {
      int m = wm + mt * 16 + i;
      int s0 = (2 * q) ^ (i & 7), s1 = (2 * q + 1) ^ (i & 7);
      f32x4 lo = *(const f32x4*)&Asb[m * 32 + s0 * 4];
      f32x4 hi = *(const f32x4*)&Asb[m * 32 + s1 * 4];
      unsigned u0 = __float_as_uint(lo[0]) + 0x8000u, u1 = __float_as_uint(lo[1]) + 0x8000u;
      unsigned u2 = __float_as_uint(lo[2]) + 0x8000u, u3 = __float_as_uint(lo[3]) + 0x8000u;
      unsigned u4 = __float_as_uint(hi[0]) + 0x8000u, u5 = __float_as_uint(hi[1]) + 0x8000u;
      unsigned u6 = __float_as_uint(hi[2]) + 0x8000u, u7 = __float_as_uint(hi[3]) + 0x8000u;
      unsigned pk0 = __builtin_amdgcn_perm(u1, u0, 0x07060302u);
      unsigned pk1 = __builtin_amdgcn_perm(u3, u2, 0x07060302u);
      unsigned pk2 = __builtin_amdgcn_perm(u5, u4, 0x07060302u);
      unsigned pk3 = __builtin_amdgcn_perm(u7, u6, 0x07060302u);
      unsigned pks[4] = {pk0, pk1, pk2, pk3};
      a[mt] = *(short8*)pks;
    }
#pragma unroll
    for (int nt = 0; nt < 4; nt++)
      bfr[nt] = *(const short8*)&Bsb[(wn + nt * 16 + i) * 32 + csb * 8];
    if (k < 6) stage(k + 2, (k + 2) % 3);
#pragma unroll
    for (int mt = 0; mt < 4; mt++)
#pragma unroll
      for (int nt = 0; nt < 4; nt++)
        acc[mt][nt] = __builtin_amdgcn_mfma_f32_16x16x32_bf16(a[mt], bfr[nt], acc[mt][nt], 0, 0, 0);
  }

  if (blockIdx.y < 4) {
    // Q|K: bias (+QSCALE for Q) and line-friendly QKp store
    float scale = (n0 < 256) ? QSCALE : 1.0f;
#pragma unroll
    for (int nt = 0; nt < 4; nt++) {
      int f = n0 + wn + nt * 16 + i;
      float bias = BCAT[f];
#pragma unroll
      for (int mt = 0; mt < 4; mt++) {
#pragma unroll
        for (int r = 0; r < 4; r++) {
          int token = m0 + wm + mt * 16 + q * 4 + r;
          QKp[(size_t)token * F2 + f] = f2bf((acc[mt][nt][r] + bias) * scale);
        }
      }
    }
  } else {
    // V: bias, transpose via LDS (TT[f_local][m_local], stride 136), write Vt
    int vb = blockIdx.y - 4;               // 0 or 1
    short* TT = (short*)smem;              // 128*136*2 = 34,816 B (fits)
    __syncthreads();                       // all slab reads done
#pragma unroll
    for (int nt = 0; nt < 4; nt++) {
      int fl = wn + nt * 16 + i;
      float bias = BCAT[512 + vb * 128 + fl];
#pragma unroll
      for (int mt = 0; mt < 4; mt++) {
#pragma unroll
        for (int r = 0; r < 4; r++) {
          int ml = wm + mt * 16 + q * 4 + r;
          TT[fl * 136 + ml] = (short)f2bf(acc[mt][nt][r] + bias);
        }
      }
    }
    __syncthreads();
    int fl = tid >> 1, half = tid & 1;
    int fg = vb * 128 + fl;
    int hh = fg >> 5, dd = fg & 31;
    int bb = m0 >> 9, tt0 = m0 & 511;
    unsigned short* dstrow = Vt + ((size_t)(bb * NH + hh) * HD + dd) * T_ + tt0 + half * 64;
#pragma unroll
    for (int j = 0; j < 8; j++) {
      short8 v = *(const short8*)&TT[fl * 136 + half * 64 + j * 8];
      *(short8*)&dstrow[j * 8] = v;
    }
  }
}

// ---------------- kernel 2: attention, P software-pipelined -------------------
// 1024 blocks x 256 thr (4 waves); wave = 64 t-rows of one (b,h); s-step 32.
// Double-buffered pscr: iter reads P(it) (written last iter), computes P(it+1).
// K/V/batch register prefetch. Mask pre-exp; denom via ones-column MFMA.
__global__ __launch_bounds__(256) void attn_kernel(
    const unsigned short* __restrict__ QKp, const unsigned short* __restrict__ Vt,
    const int* __restrict__ batch, unsigned short* __restrict__ Y) {
  __shared__ __align__(16) short pscr[4][2][64 * PSTR];  // 40,960 B
  __shared__ int sbat[T_];                               //  2,048 B
  int tid = threadIdx.x, w = tid >> 6, lane = tid & 63;
  int i = lane & 15, q = lane >> 4;
  int bx = blockIdx.x;
  int bh = ((bx >> 4) << 3) | (bx & 7);   // halves of a bh: 8 apart (same XCD)
  int half = (bx >> 3) & 1;
  int b = bh >> 3, h = bh & 7;
  int t0 = half * 256 + w * 64;
  const unsigned short* Tok = QKp + (size_t)b * T_ * F2;
  const unsigned short* Vb = Vt + (size_t)bh * HD * T_;

  *(int2*)&sbat[tid * 2] = *(const int2*)&batch[b * T_ + tid * 2];
  __syncthreads();

  short8 qf[4];
  int btv[4][4];
#pragma unroll
  for (int mt = 0; mt < 4; mt++)
    qf[mt] = *(const short8*)&Tok[(size_t)(t0 + mt * 16 + i) * F2 + h * HD + q * 8];
#pragma unroll
  for (int mt = 0; mt < 4; mt++) {
    int4 t4 = *(int4*)&sbat[t0 + mt * 16 + q * 4];
    btv[mt][0] = t4.x; btv[mt][1] = t4.y; btv[mt][2] = t4.z; btv[mt][3] = t4.w;
  }

  unsigned short ob = (i == 0) ? (unsigned short)0x3F80 : (unsigned short)0;
  short8 ones = {(short)ob, (short)ob, (short)ob, (short)ob,
                 (short)ob, (short)ob, (short)ob, (short)ob};

  f32x4 zf = {0.f, 0.f, 0.f, 0.f};
  f32x4 o[4][2], lacc[4];
#pragma unroll
  for (int mt = 0; mt < 4; mt++) {
    o[mt][0] = zf; o[mt][1] = zf; lacc[mt] = zf;
  }

  const unsigned short* Kcol = Tok + 256 + h * HD + q * 8;

  // computeP(block s0 -> buffer buf) using given K frags / seg ids
  auto computeP = [&](int buf, short8 ka, short8 kb, int ba, int bb2) {
    short* pw = &pscr[w][buf][0];
#pragma unroll
    for (int mt = 0; mt < 4; mt++) {
      f32x4 st0 = __builtin_amdgcn_mfma_f32_16x16x32_bf16(qf[mt], ka, zf, 0, 0, 0);
      f32x4 st1 = __builtin_amdgcn_mfma_f32_16x16x32_bf16(qf[mt], kb, zf, 0, 0, 0);
#pragma unroll
      for (int r = 0; r < 4; r++) {
        float m0v = (btv[mt][r] == ba) ? -1e9f : st0[r];
        float m1v = (btv[mt][r] == bb2) ? -1e9f : st1[r];
        unsigned e0 = __float_as_uint(__builtin_amdgcn_exp2f(m0v));
        unsigned e1 = __float_as_uint(__builtin_amdgcn_exp2f(m1v));
        unsigned pk = __builtin_amdgcn_perm(e1, e0, 0x07060302u);
        *(unsigned*)&pw[(mt * 16 + q * 4 + r) * PSTR + 2 * i] = pk;
      }
    }
  };

  short8 kn0, kn1, vc0, vc1, vn0, vn1;
  int bn0, bn1;
  // prologue: P(0) -> buf0; prefetch K(1), V(0), V(1)
  {
    short8 ka = *(const short8*)&Kcol[(size_t)(2 * i) * F2];
    short8 kb = *(const short8*)&Kcol[(size_t)(2 * i + 1) * F2];
    int ba = sbat[2 * i], bb2 = sbat[2 * i + 1];
    computeP(0, ka, kb, ba, bb2);
  }
  vc0 = *(const short8*)&Vb[(size_t)i * T_ + q * 8];
  vc1 = *(const short8*)&Vb[(size_t)(16 + i) * T_ + q * 8];
  kn0 = *(const short8*)&Kcol[(size_t)(32 + 2 * i) * F2];
  kn1 = *(const short8*)&Kcol[(size_t)(32 + 2 * i + 1) * F2];
  bn0 = sbat[32 + 2 * i]; bn1 = sbat[32 + 2 * i + 1];
  vn0 = *(const short8*)&Vb[(size_t)i * T_ + 32 + q * 8];
  vn1 = *(const short8*)&Vb[(size_t)(16 + i) * T_ + 32 + q * 8];

  for (int it = 0; it < 16; it++) {
    int cur = it & 1;
    short* pr = &pscr[w][cur][0];
    short8 pa[4];
#pragma unroll
    for (int mt = 0; mt < 4; mt++)
      pa[mt] = *(short8*)&pr[(mt * 16 + i) * PSTR + q * 8];
    if (it < 15) {
      computeP(1 - cur, kn0, kn1, bn0, bn1);
      if (it < 14) {
        int s2 = (it + 2) * 32;
        kn0 = *(const short8*)&Kcol[(size_t)(s2 + 2 * i) * F2];
        kn1 = *(const short8*)&Kcol[(size_t)(s2 + 2 * i + 1) * F2];
        bn0 = sbat[s2 + 2 * i]; bn1 = sbat[s2 + 2 * i + 1];
      }
    }
#pragma unroll
    for (int mt = 0; mt < 4; mt++) {
      o[mt][0] = __builtin_amdgcn_mfma_f32_16x16x32_bf16(pa[mt], vc0, o[mt][0], 0, 0, 0);
      o[mt][1] = __builtin_amdgcn_mfma_f32_16x16x32_bf16(pa[mt], vc1, o[mt][1], 0, 0, 0);
      lacc[mt] = __builtin_amdgcn_mfma_f32_16x16x32_bf16(pa[mt], ones, lacc[mt], 0, 0, 0);
    }
    vc0 = vn0; vc1 = vn1;
    if (it < 14) {
      int s2 = (it + 2) * 32;
      vn0 = *(const short8*)&Vb[(size_t)i * T_ + s2 + q * 8];
      vn1 = *(const short8*)&Vb[(size_t)(16 + i) * T_ + s2 + q * 8];
    }
  }

#pragma unroll
  for (int mt = 0; mt < 4; mt++) {
#pragma unroll
    for (int r = 0; r < 4; r++) {
      float lv = __shfl(lacc[mt][r], lane & 48, 64);  // col 0 of this row-quad
      float inv = __builtin_amdgcn_rcpf(lv);
      size_t yb = ((size_t)b * T_ + t0 + mt * 16 + q * 4 + r) * DM + h * HD;
      Y[yb + i] = f2bf(o[mt][0][r] * inv);
      Y[yb + 16 + i] = f2bf(o[mt][1][r] * inv);
    }
  }
}

// ---------------- kernel 3: output GEMM, gathered A rows (r6 version) ---------
// out[i][f] = sum_c Y[inv[i]][c] * Wp[f][c] + bp[f]; M=24576,N=256,K=256.
__global__ __launch_bounds__(256) void out_gemm(
    const short* __restrict__ Y, const short* __restrict__ WPb,
    const float* __restrict__ bp, const int* __restrict__ inv,
    float* __restrict__ out) {
  __shared__ __align__(16) char smem[3 * 16384];
  int tid = threadIdx.x;
  int lane = tid & 63, w = tid >> 6;
  int i = lane & 15, q = lane >> 4;
  int m0 = blockIdx.x * 128, n0 = blockIdx.y * 128;
  int wm = (w & 1) * 64, wn = (w >> 1) * 64;
  int csa = q ^ ((i >> 1) & 3);

  int iv0 = inv[m0 + (tid >> 2)];
  int iv1 = inv[m0 + 64 + (tid >> 2)];

  f32x4 zf = {0.f, 0.f, 0.f, 0.f};
  f32x4 acc[4][4];
#pragma unroll
  for (int mt = 0; mt < 4; mt++)
#pragma unroll
    for (int nt = 0; nt < 4; nt++) acc[mt][nt] = zf;

  auto stage = [&](int k, int s) {
#pragma unroll
    for (int p = 0; p < 2; p++) {
      int U = p * 256 + tid;
      int row = U >> 2, c = U & 3;
      int cs = c ^ ((row >> 1) & 3);
      int iv = p ? iv1 : iv0;
      gl_lds16(Y + (size_t)iv * DM + k * 32 + cs * 8, smem + s * 16384 + U * 16);
      gl_lds16(WPb + (size_t)(n0 + row) * DM + k * 32 + cs * 8,
               smem + s * 16384 + 8192 + U * 16);
    }
  };

  stage(0, 0);
  stage(1, 1);
#pragma unroll
  for (int k = 0; k < 8; k++) {
    if (k == 7)
      asm volatile("s_waitcnt vmcnt(0) lgkmcnt(0)\ns_barrier" ::: "memory");
    else
      asm volatile("s_waitcnt vmcnt(4) lgkmcnt(0)\ns_barrier" ::: "memory");
    const short* Asb = (const short*)(smem + (k % 3) * 16384);
    const short* Bsb = Asb + 4096;
    short8 a[4], bfr[4];
#pragma unroll
    for (int mt = 0; mt < 4; mt++)
      a[mt] = *(const short8*)&Asb[(wm + mt * 16 + i) * 32 + csa * 8];
#pragma unroll
    for (int nt = 0; nt < 4; nt++)
      bfr[nt] = *(const short8*)&Bsb[(wn + nt * 16 + i) * 32 + csa * 8];
    if (k < 6) stage(k + 2, (k + 2) % 3);
#pragma unroll
    for (int mt = 0; mt < 4; mt++)
#pragma unroll
      for (int nt = 0; nt < 4; nt++)
        acc[mt][nt] = __builtin_amdgcn_mfma_f32_16x16x32_bf16(a[mt], bfr[nt], acc[mt][nt], 0, 0, 0);
  }

#pragma unroll
  for (int nt = 0; nt < 4; nt++) {
    int f = n0 + wn + nt * 16 + i;
    float bias = bp[f];
#pragma unroll
    for (int mt = 0; mt < 4; mt++) {
#pragma unroll
      for (int r = 0; r < 4; r++) {
        int row = m0 + wm + mt * 16 + q * 4 + r;
        out[(size_t)row * DM + f] = acc[mt][nt][r] + bias;
      }
    }
  }
}

// ---------------- launch ----------------
extern "C" void kernel_launch(void* const* d_in, const int* in_sizes, int n_in,
                              void* d_out, int out_size, void* d_ws, size_t ws_size,
                              hipStream_t stream) {
  const float* x = (const float*)d_in[0];
  const float* Wq = (const float*)d_in[1];
  const float* bq = (const float*)d_in[2];
  const float* Wk = (const float*)d_in[3];
  const float* bk = (const float*)d_in[4];
  const float* Wv = (const float*)d_in[5];
  const float* bv = (const float*)d_in[6];
  const float* Wp = (const float*)d_in[7];
  const float* bp = (const float*)d_in[8];
  const int* idx = (const int*)d_in[9];
  const int* batch = (const int*)d_in[10];
  const int* inv = (const int*)d_in[11];
  float* out = (float*)d_out;

  char* ws = (char*)d_ws;
  short* WCAT = (short*)(ws + 0);                          //    393,216 B
  short* WPb = (short*)(ws + 393216);                      //    131,072 B
  float* BCAT = (float*)(ws + 524288);                     //      3,072 B
  unsigned short* QKp = (unsigned short*)(ws + 1048576);   // 33,554,432 B
  unsigned short* Vt = (unsigned short*)(ws + 34603008);   // 16,777,216 B
  unsigned short* Yb = (unsigned short*)(ws + 51380224);   // 16,777,216 B
  // total ws use: 68,157,440 B

  pack_kernel<<<128, 256, 0, stream>>>(Wq, Wk, Wv, Wp, bq, bk, bv,
                                       WCAT, WPb, BCAT);
  qkv_gemm<<<dim3(256, 6), 256, 0, stream>>>(x, idx, WCAT, BCAT, QKp, Vt);
  attn_kernel<<<1024, 256, 0, stream>>>(QKp, Vt, batch, Yb);
  out_gemm<<<dim3(192, 2), 256, 0, stream>>>((const short*)Yb, WPb, bp, inv, out);
}